// Round 6
// baseline (528.295 us; speedup 1.0000x reference)
//
#include <hip/hip_runtime.h>
#include <hip/hip_bf16.h>
#include <cstdint>
#include <cstddef>

typedef __bf16 bf16x8 __attribute__((ext_vector_type(8)));
typedef float floatx4 __attribute__((ext_vector_type(4)));

#define MFMA(a, b, c) __builtin_amdgcn_mfma_f32_16x16x32_bf16((a), (b), (c), 0, 0, 0)
#define WAITVM(N) asm volatile("s_waitcnt vmcnt(" #N ")" ::: "memory")
#define BARRIER() do { asm volatile("" ::: "memory"); __builtin_amdgcn_s_barrier(); asm volatile("" ::: "memory"); } while (0)

__device__ __forceinline__ unsigned short f2bf(float f) {
  unsigned u = __builtin_bit_cast(unsigned, f);
  u += 0x7fffu + ((u >> 16) & 1u);
  return (unsigned short)(u >> 16);
}
__device__ __forceinline__ float bf2f(unsigned short h) {
  unsigned u = ((unsigned)h) << 16;
  return __builtin_bit_cast(float, u);
}
__device__ __forceinline__ float fast_exp2(float x) {
#if __has_builtin(__builtin_amdgcn_exp2f)
  return __builtin_amdgcn_exp2f(x);
#else
  return exp2f(x);
#endif
}

// async 16B global -> LDS DMA. LDS dest = wave-uniform base + lane*16.
__device__ __forceinline__ void gl2lds16(const unsigned short* g, unsigned short* l) {
  __builtin_amdgcn_global_load_lds(
      (const __attribute__((address_space(1))) unsigned int*)g,
      (__attribute__((address_space(3))) unsigned int*)l, 16, 0, 0);
}

// ---------------- fp32 -> bf16 convert (x) ----------------
__global__ void convert_f32_bf16(const float* __restrict__ src,
                                 unsigned short* __restrict__ dst, int n4) {
  int i = blockIdx.x * 256 + threadIdx.x;
  if (i >= n4) return;
  float4 f = ((const float4*)src)[i];
  ushort4 o;
  o.x = f2bf(f.x); o.y = f2bf(f.y); o.z = f2bf(f.z); o.w = f2bf(f.w);
  ((ushort4*)dst)[i] = o;
}

// ---------------- fp32 (K x N) -> bf16 transposed (N x K), 64x64 tiles ----------------
__global__ void transpose_f32_bf16(const float* __restrict__ src,
                                   unsigned short* __restrict__ dst, int K, int N) {
  __shared__ float tile[64 * 65];
  int tn = blockIdx.x * 64, tk = blockIdx.y * 64;
  int r = threadIdx.x >> 4;          // 0..15
  int c4 = (threadIdx.x & 15) * 4;   // 0,4,..,60
#pragma unroll
  for (int i = 0; i < 4; i++) {
    float4 f = *(const float4*)&src[(size_t)(tk + r + 16 * i) * N + tn + c4];
    float* tr = &tile[(r + 16 * i) * 65 + c4];
    tr[0] = f.x; tr[1] = f.y; tr[2] = f.z; tr[3] = f.w;
  }
  __syncthreads();
#pragma unroll
  for (int i = 0; i < 4; i++) {
    ushort4 o;
    o.x = f2bf(tile[(c4 + 0) * 65 + r + 16 * i]);
    o.y = f2bf(tile[(c4 + 1) * 65 + r + 16 * i]);
    o.z = f2bf(tile[(c4 + 2) * 65 + r + 16 * i]);
    o.w = f2bf(tile[(c4 + 3) * 65 + r + 16 * i]);
    *(ushort4*)&dst[(size_t)(tn + r + 16 * i) * K + tk + c4] = o;
  }
}

// ---------------- 2-phase dbuf bf16 GEMM: C = A(MxK) * Bt(NxK)^T ----------------
// 128x128 tile, BK=64, 256 threads (4 waves 2x2, 64x64 per wave), LDS 64 KB
// -> 2 blocks/CU (multi-block overlap, the R0-measured winner) PLUS T3
// stage-ahead: tile T+1 staged into buf^1 while computing tile T; counted
// WAITVM(8) at tile start drains only tile T (T+1's 8 loads stay in flight).
// Raw s_barrier (NOT __syncthreads) so the compiler can't re-insert vmcnt(0).
// Hazard proof: buf^1's last readers = tile T-1 ds_reads, drained (per-wave
// lgkm before MFMA use) before T-1's end BARRIER, which precedes the stage.
// Source-side XOR colgroup swizzle (validated SQ_LDS_BANK_CONFLICT=0).
template <bool F32OUT>
__global__ __launch_bounds__(256, 2) void gemm2p(
    const unsigned short* __restrict__ A,
    const unsigned short* __restrict__ Bt,
    void* __restrict__ C, int M, int N, int K) {
  __shared__ alignas(16) unsigned short Al[2 * 128 * 64];
  __shared__ alignas(16) unsigned short Bl[2 * 128 * 64];
  const int tid = threadIdx.x;
  const int w = tid >> 6, L = tid & 63;
  const int lr = L & 15, lg = L >> 4, lr7 = lr & 7;
  const int bm = blockIdx.y * 128, bn = blockIdx.x * 128;
  const int wm = (w >> 1) * 64, wn = (w & 1) * 64;
  const int NT = K >> 6;

  // staging map: thread -> (row = tid>>3 within 32-row chunk, colgroup = tid&7)
  const int srow = tid >> 3, scg = tid & 7;
  const unsigned short* Ag = &A[(size_t)(bm + srow) * K + ((scg ^ (srow & 7)) * 8)];
  const unsigned short* Bg = &Bt[(size_t)(bn + srow) * K + ((scg ^ (srow & 7)) * 8)];
  unsigned short* AlT = Al + tid * 8;
  unsigned short* BlT = Bl + tid * 8;

  // prologue: stage tile 0 -> buf 0 (8 issues/thread-wave)
#pragma unroll
  for (int c = 0; c < 4; c++) {
    gl2lds16(Ag + (size_t)(c * 32) * K, AlT + c * 2048);
    gl2lds16(Bg + (size_t)(c * 32) * K, BlT + c * 2048);
  }

  floatx4 acc[4][4] = {};

  for (int T = 0; T < NT; ++T) {
    const int buf = T & 1;
    // stage tile T+1 into buf^1 (its tile T-1 readers drained before last barrier)
    if (T + 1 < NT) {
      const size_t kofs = (size_t)(T + 1) * 64;
      unsigned short* Ad = AlT + (buf ^ 1) * 8192;
      unsigned short* Bd = BlT + (buf ^ 1) * 8192;
#pragma unroll
      for (int c = 0; c < 4; c++) {
        gl2lds16(Ag + (size_t)(c * 32) * K + kofs, Ad + c * 2048);
        gl2lds16(Bg + (size_t)(c * 32) * K + kofs, Bd + c * 2048);
      }
      WAITVM(8);       // outstanding = T(8)+T+1(8); drains tile T only
    } else {
      WAITVM(0);       // last tile: drain it
    }
    BARRIER();         // collective: every wave's tile-T loads landed

    const unsigned short* Ab = Al + buf * 8192;
    const unsigned short* Bb = Bl + buf * 8192;
#pragma unroll
    for (int kk = 0; kk < 2; kk++) {
      bf16x8 af[4], bfr[4];
#pragma unroll
      for (int i = 0; i < 4; i++) {
        af[i]  = *(const bf16x8*)&Ab[(wm + i * 16 + lr) * 64 + (((kk * 4 + lg) ^ lr7) * 8)];
        bfr[i] = *(const bf16x8*)&Bb[(wn + i * 16 + lr) * 64 + (((kk * 4 + lg) ^ lr7) * 8)];
      }
#pragma unroll
      for (int mi = 0; mi < 4; mi++)
#pragma unroll
        for (int ni = 0; ni < 4; ni++)
          acc[mi][ni] = MFMA(af[mi], bfr[ni], acc[mi][ni]);
    }
    BARRIER();         // all waves' reads of buf done before T+2 stages into it
  }

#pragma unroll
  for (int mi = 0; mi < 4; mi++) {
#pragma unroll
    for (int ni = 0; ni < 4; ni++) {
#pragma unroll
      for (int r = 0; r < 4; r++) {
        size_t row = bm + wm + mi * 16 + lg * 4 + r;
        size_t col = bn + wn + ni * 16 + lr;
        float v = acc[mi][ni][r];
        if constexpr (F32OUT) ((float*)C)[row * N + col] = v;
        else ((unsigned short*)C)[row * N + col] = f2bf(v);
      }
    }
  }
}

// ---------------- RoPE in place on bf16 rows, vectorized x4 ----------------
__global__ void rope_kernel(unsigned short* __restrict__ X, const float* __restrict__ cs,
                            int H, int rowStride, int colOff, float scale) {
  int idx = blockIdx.x * 256 + threadIdx.x;
  int dg = idx & 15;            // 4-wide d group: d = dg*4..dg*4+3
  int h = (idx >> 4) % H;
  int s = idx / (16 * H);
  size_t base = (size_t)s * rowStride + colOff + (size_t)h * 128 + dg * 4;
  ushort4 xa = *(const ushort4*)&X[base];
  ushort4 xb = *(const ushort4*)&X[base + 64];
  float4 c = *(const float4*)&cs[s * 64 + dg * 4];
  float4 sn = *(const float4*)&cs[2048 * 64 + s * 64 + dg * 4];
  ushort4 oa, ob;
  {
    float x1 = bf2f(xa.x), x2 = bf2f(xb.x);
    oa.x = f2bf((x1 * c.x + x2 * sn.x) * scale);
    ob.x = f2bf((x2 * c.x - x1 * sn.x) * scale);
  }
  {
    float x1 = bf2f(xa.y), x2 = bf2f(xb.y);
    oa.y = f2bf((x1 * c.y + x2 * sn.y) * scale);
    ob.y = f2bf((x2 * c.y - x1 * sn.y) * scale);
  }
  {
    float x1 = bf2f(xa.z), x2 = bf2f(xb.z);
    oa.z = f2bf((x1 * c.z + x2 * sn.z) * scale);
    ob.z = f2bf((x2 * c.z - x1 * sn.z) * scale);
  }
  {
    float x1 = bf2f(xa.w), x2 = bf2f(xb.w);
    oa.w = f2bf((x1 * c.w + x2 * sn.w) * scale);
    ob.w = f2bf((x2 * c.w - x1 * sn.w) * scale);
  }
  *(ushort4*)&X[base] = oa;
  *(ushort4*)&X[base + 64] = ob;
}

// ---------------- V (cols 5120.. of QKV, stride 6144) -> Vt (8,128,2048) ----------------
__global__ void v_transpose(const unsigned short* __restrict__ QKV,
                            unsigned short* __restrict__ Vt) {
  __shared__ unsigned short tile[32][33];
  int h = blockIdx.z;
  int s0 = blockIdx.x * 32, d0 = blockIdx.y * 32;
  int c = threadIdx.x & 31, r0 = threadIdx.x >> 5;
#pragma unroll
  for (int i = 0; i < 32; i += 8)
    tile[r0 + i][c] = QKV[(size_t)(s0 + r0 + i) * 6144 + 5120 + h * 128 + d0 + c];
  __syncthreads();
#pragma unroll
  for (int i = 0; i < 32; i += 8)
    Vt[(size_t)(h * 128 + d0 + r0 + i) * 2048 + s0 + c] = tile[c][r0 + i];
}

// ---------------- causal flash attention (v3: pipelined K/V staging) ----------------
// Block = 2 heads (same KV group) x 64 q-rows; 4 waves. K double-buffered
// (stage K[t+1] after QK^T, lands under PV + next QK); V single-buffered,
// staged at tile entry, awaited by counted WAITVM(4) after QK^T+exp.
// vmcnt ledger (per wave): entry outstanding = K[t](4) -> WAITVM(0) (issued a
// full PV earlier, cheap); mid outstanding = V[t](4)+K[t+1](4) -> WAITVM(4)
// drains V (older). t==qb: no K-stage -> WAITVM(0) at mid. Raw s_barrier only.
// Hazards: V restage at entry is safe because tile t-1 PV reads drained
// (per-wave lgkm) before each wave reached the entry BARRIER; K[t+1] targets
// buffer last read at tile t-1 (drained before t-1's mid BARRIER).
__global__ __launch_bounds__(256) void flash_kernel(
    const unsigned short* __restrict__ QKV,  // (2048, 6144) roped; Q pre-scaled
    const unsigned short* __restrict__ Vt,   // (8, 128, 2048)
    unsigned short* __restrict__ O) {        // (2048, 4096)
  constexpr int PSTR = 72;
  __shared__ alignas(16) unsigned short Klds[2 * 64 * 128];   // 32 KB dbuf, swz cg16
  __shared__ alignas(16) unsigned short Vlds[128 * 64];       // 16 KB, swz cg8
  __shared__ alignas(16) unsigned short Plds[4 * 32 * PSTR];  // 18 KB wave-private
  const int tid = threadIdx.x, w = tid >> 6, L = tid & 63;
  const int lr = L & 15, lg = L >> 4;
  const int bid = blockIdx.x;
  const int hk = bid & 7;
  const int hp = (bid >> 3) & 1;
  const int qb = 31 - (bid >> 4);          // heavy blocks dispatch first
  const int hq = hk * 4 + hp * 2 + (w & 1);
  const int qr0 = qb * 64 + (w >> 1) * 32; // wave's 32 q-rows
  const unsigned short* Kg = QKV + 4096;

  // K staging: row=flat>>4, lcg=flat&15, source cg = lcg ^ (row&15)
  const int k_row = tid >> 4, k_lcg = tid & 15;
  const unsigned short* KgT = &Kg[(size_t)k_row * 6144 + hk * 128 + ((k_lcg ^ (k_row & 15)) * 8)];
  unsigned short* KlT = &Klds[k_row * 128 + k_lcg * 8];
  // V staging: row=flat>>3 (dh), lcg=flat&7, source cg = lcg ^ (row&7)
  const int v_row = tid >> 3, v_lcg = tid & 7;
  const unsigned short* VgT = &Vt[(size_t)(hk * 128 + v_row) * 2048 + ((v_lcg ^ (v_row & 7)) * 8)];
  unsigned short* VlT = &Vlds[v_row * 64 + v_lcg * 8];

  // prologue: stage K[0] into K buffer 0
#pragma unroll
  for (int i = 0; i < 4; i++)
    gl2lds16(KgT + (size_t)(i * 16) * 6144, KlT + i * 16 * 128);

  bf16x8 qf[2][4];
#pragma unroll
  for (int mi = 0; mi < 2; mi++)
#pragma unroll
    for (int c = 0; c < 4; c++)
      qf[mi][c] = *(const bf16x8*)&QKV[(size_t)(qr0 + mi * 16 + lr) * 6144 + hq * 128 + c * 32 + lg * 8];

  floatx4 oacc[2][8] = {};
  float l_lane[2][4] = {};
  unsigned short* pw = &Plds[w * 32 * PSTR];

  for (int t = 0; t <= qb; t++) {
    const int kv0 = t * 64;
    const int kb = t & 1;
    WAITVM(0);     // K[t] landed (only K[t] outstanding at entry; also drains qf at t=0)
    BARRIER();     // collective: K[t] visible; all waves' V[t-1] PV reads done
    // stage V[t] (single buffer, safe per barrier above)
#pragma unroll
    for (int i = 0; i < 4; i++)
      gl2lds16(VgT + kv0 + (size_t)(i * 32) * 2048, VlT + i * 32 * 64);

    const unsigned short* Kl = &Klds[kb * (64 * 128)];
#pragma unroll
    for (int nt = 0; nt < 4; nt++) {
      bf16x8 kf[4];
#pragma unroll
      for (int c = 0; c < 4; c++)
        kf[c] = *(const bf16x8*)&Kl[(nt * 16 + lr) * 128 + (((c * 4 + lg) ^ lr) * 8)];
      floatx4 sc[2];
#pragma unroll
      for (int mi = 0; mi < 2; mi++) {
        floatx4 a = {};
#pragma unroll
        for (int c = 0; c < 4; c++) a = MFMA(qf[mi][c], kf[c], a);
        sc[mi] = a;
      }
      if (t == qb) {  // diagonal tile: causal mask
#pragma unroll
        for (int mi = 0; mi < 2; mi++)
#pragma unroll
          for (int r = 0; r < 4; r++)
            if (kv0 + nt * 16 + lr > qr0 + mi * 16 + lg * 4 + r) sc[mi][r] = -3e38f;
      }
#pragma unroll
      for (int mi = 0; mi < 2; mi++)
#pragma unroll
        for (int r = 0; r < 4; r++) {
          float p = fast_exp2(sc[mi][r]);
          l_lane[mi][r] += p;
          pw[(mi * 16 + lg * 4 + r) * PSTR + nt * 16 + lr] = f2bf(p);
        }
    }

    // stage K[t+1] into the other K buffer (its readers drained at tile t-1)
    if (t < qb) {
      unsigned short* Kd = KlT + (kb ^ 1) * (64 * 128);
#pragma unroll
      for (int i = 0; i < 4; i++)
        gl2lds16(KgT + (size_t)(kv0 + 64 + i * 16) * 6144, Kd + i * 16 * 128);
      WAITVM(4);   // drains V[t] (older); K[t+1]'s 4 stay in flight
    } else {
      WAITVM(0);   // last tile: drain V[t]
    }
    BARRIER();     // collective: V[t] visible

    // P (wave-private, in-order DS) -> A-fragments
    bf16x8 pf[2][2];
#pragma unroll
    for (int mi = 0; mi < 2; mi++)
#pragma unroll
      for (int c = 0; c < 2; c++)
        pf[mi][c] = *(const bf16x8*)&pw[(mi * 16 + lr) * PSTR + c * 32 + lg * 8];

#pragma unroll
    for (int n = 0; n < 8; n++) {
#pragma unroll
      for (int c = 0; c < 2; c++) {
        bf16x8 vf = *(const bf16x8*)&Vlds[(n * 16 + lr) * 64 + (((c * 4 + lg) ^ (lr & 7)) * 8)];
#pragma unroll
        for (int mi = 0; mi < 2; mi++) oacc[mi][n] = MFMA(pf[mi][c], vf, oacc[mi][n]);
      }
    }
  }

  // row-sum across the 16 lr lanes (masks 1..8 stay within lr group)
  float linv[2][4];
#pragma unroll
  for (int mi = 0; mi < 2; mi++)
#pragma unroll
    for (int r = 0; r < 4; r++) {
      float l = l_lane[mi][r];
      l += __shfl_xor(l, 1);
      l += __shfl_xor(l, 2);
      l += __shfl_xor(l, 4);
      l += __shfl_xor(l, 8);
      linv[mi][r] = 1.0f / l;
    }

#pragma unroll
  for (int mi = 0; mi < 2; mi++)
#pragma unroll
    for (int n = 0; n < 8; n++)
#pragma unroll
      for (int r = 0; r < 4; r++) {
        size_t row = qr0 + mi * 16 + lg * 4 + r;
        size_t col = (size_t)hq * 128 + n * 16 + lr;
        O[row * 4096 + col] = f2bf(oacc[mi][n][r] * linv[mi][r]);
      }
}

extern "C" void kernel_launch(void* const* d_in, const int* in_sizes, int n_in,
                              void* d_out, int out_size, void* d_ws, size_t ws_size,
                              hipStream_t stream) {
  const float* x  = (const float*)d_in[0];
  const float* cs = (const float*)d_in[1];
  const float* wq = (const float*)d_in[2];
  const float* wk = (const float*)d_in[3];
  const float* wv = (const float*)d_in[4];
  const float* wo = (const float*)d_in[5];
  float* out = (float*)d_out;

  char* ws = (char*)d_ws;
  unsigned short* xb   = (unsigned short*)(ws);               // 16 MB  x bf16
  unsigned short* wqt  = (unsigned short*)(ws + 16777216);    // 32 MB  wq^T } contiguous
  unsigned short* wkt  = (unsigned short*)(ws + 50331648);    // 8 MB   wk^T } B for fused
  unsigned short* wvt  = (unsigned short*)(ws + 58720256);    // 8 MB   wv^T } QKV gemm
  unsigned short* wot  = (unsigned short*)(ws + 67108864);    // 32 MB  wo^T
  unsigned short* QKVb = (unsigned short*)(ws + 100663296);   // 24 MB  [Q|K|V]
  unsigned short* Vtb  = (unsigned short*)(ws + 125829120);   // 4 MB   V^T
  unsigned short* Ob   = xb;  // alias: xb dead after QKV gemm

  convert_f32_bf16<<<8192, 256, 0, stream>>>(x, xb, 2097152);
  transpose_f32_bf16<<<dim3(64, 64), 256, 0, stream>>>(wq, wqt, 4096, 4096);
  transpose_f32_bf16<<<dim3(16, 64), 256, 0, stream>>>(wk, wkt, 4096, 1024);
  transpose_f32_bf16<<<dim3(16, 64), 256, 0, stream>>>(wv, wvt, 4096, 1024);
  transpose_f32_bf16<<<dim3(64, 64), 256, 0, stream>>>(wo, wot, 4096, 4096);

  // QKV: 128x128 tiles, grid (48,16) = 768 blocks (~3/CU resident 2 by LDS)
  gemm2p<false><<<dim3(48, 16), 256, 0, stream>>>(xb, wqt, QKVb, 2048, 6144, 4096);

  // Q scale folds softmax 1/sqrt(128) AND log2(e) for exp2-based softmax
  rope_kernel<<<4096, 256, 0, stream>>>(QKVb, cs, 32, 6144, 0, 0.12751743f);
  rope_kernel<<<1024, 256, 0, stream>>>(QKVb, cs, 8, 6144, 4096, 1.0f);

  v_transpose<<<dim3(64, 4, 8), 256, 0, stream>>>(QKVb, Vtb);

  flash_kernel<<<512, 256, 0, stream>>>(QKVb, Vtb, Ob);

  // O-proj: 128x128 tiles, grid (32,16) = 512 blocks (2/CU)
  gemm2p<true><<<dim3(32, 16), 256, 0, stream>>>(Ob, wot, out, 2048, 4096, 4096);
}

// Round 7
// 488.204 us; speedup vs baseline: 1.0821x; 1.0821x over previous
//
#include <hip/hip_runtime.h>
#include <hip/hip_bf16.h>
#include <cstdint>
#include <cstddef>

typedef __bf16 bf16x8 __attribute__((ext_vector_type(8)));
typedef float floatx4 __attribute__((ext_vector_type(4)));

#define MFMA(a, b, c) __builtin_amdgcn_mfma_f32_16x16x32_bf16((a), (b), (c), 0, 0, 0)
#define WAITVM(N) asm volatile("s_waitcnt vmcnt(" #N ")" ::: "memory")
#define BARRIER() do { asm volatile("" ::: "memory"); __builtin_amdgcn_s_barrier(); asm volatile("" ::: "memory"); } while (0)

__device__ __forceinline__ unsigned short f2bf(float f) {
  unsigned u = __builtin_bit_cast(unsigned, f);
  u += 0x7fffu + ((u >> 16) & 1u);
  return (unsigned short)(u >> 16);
}
__device__ __forceinline__ float bf2f(unsigned short h) {
  unsigned u = ((unsigned)h) << 16;
  return __builtin_bit_cast(float, u);
}
__device__ __forceinline__ float fast_exp2(float x) {
#if __has_builtin(__builtin_amdgcn_exp2f)
  return __builtin_amdgcn_exp2f(x);
#else
  return exp2f(x);
#endif
}

// async 16B global -> LDS DMA. LDS dest = wave-uniform base + lane*16.
__device__ __forceinline__ void gl2lds16(const unsigned short* g, unsigned short* l) {
  __builtin_amdgcn_global_load_lds(
      (const __attribute__((address_space(1))) unsigned int*)g,
      (__attribute__((address_space(3))) unsigned int*)l, 16, 0, 0);
}

// ---------------- fp32 -> bf16 convert (x) ----------------
__global__ void convert_f32_bf16(const float* __restrict__ src,
                                 unsigned short* __restrict__ dst, int n4) {
  int i = blockIdx.x * 256 + threadIdx.x;
  if (i >= n4) return;
  float4 f = ((const float4*)src)[i];
  ushort4 o;
  o.x = f2bf(f.x); o.y = f2bf(f.y); o.z = f2bf(f.z); o.w = f2bf(f.w);
  ((ushort4*)dst)[i] = o;
}

// ---------------- fp32 (K x N) -> bf16 transposed (N x K), 64x64 tiles ----------------
__global__ void transpose_f32_bf16(const float* __restrict__ src,
                                   unsigned short* __restrict__ dst, int K, int N) {
  __shared__ float tile[64 * 65];
  int tn = blockIdx.x * 64, tk = blockIdx.y * 64;
  int r = threadIdx.x >> 4;          // 0..15
  int c4 = (threadIdx.x & 15) * 4;   // 0,4,..,60
#pragma unroll
  for (int i = 0; i < 4; i++) {
    float4 f = *(const float4*)&src[(size_t)(tk + r + 16 * i) * N + tn + c4];
    float* tr = &tile[(r + 16 * i) * 65 + c4];
    tr[0] = f.x; tr[1] = f.y; tr[2] = f.z; tr[3] = f.w;
  }
  __syncthreads();
#pragma unroll
  for (int i = 0; i < 4; i++) {
    ushort4 o;
    o.x = f2bf(tile[(c4 + 0) * 65 + r + 16 * i]);
    o.y = f2bf(tile[(c4 + 1) * 65 + r + 16 * i]);
    o.z = f2bf(tile[(c4 + 2) * 65 + r + 16 * i]);
    o.w = f2bf(tile[(c4 + 3) * 65 + r + 16 * i]);
    *(ushort4*)&dst[(size_t)(tn + r + 16 * i) * K + tk + c4] = o;
  }
}

// ---------------- bf16 GEMM: C = A(MxK) * Bt(NxK)^T ----------------
// R0-measured best (118 us QKV, 875 TF, MfmaUtil 38.5 + VALUBusy 49):
// 128x128 tile, BK=64, 256 threads, 32 KB LDS -> ~3 blocks/CU. Multi-block
// overlap beats every phased 1-2 block/CU structure tried (R1,R2,R5,R6).
// XOR-swizzled global_load_lds staging (SQ_LDS_BANK_CONFLICT=0).
template <bool F32OUT>
__global__ __launch_bounds__(256) void gemm_bt(const unsigned short* __restrict__ A,
                        const unsigned short* __restrict__ Bt,
                        void* __restrict__ C, int M, int N, int K) {
  __shared__ alignas(16) unsigned short Alds[128 * 64];
  __shared__ alignas(16) unsigned short Blds[128 * 64];
  const int tid = threadIdx.x;
  const int w = tid >> 6, L = tid & 63;
  const int lr = L & 15, lg = L >> 4;
  const int bm = blockIdx.y * 128, bn = blockIdx.x * 128;
  const int wm = (w >> 1) * 64, wn = (w & 1) * 64;
  floatx4 acc[4][4] = {};

  const int srow = L >> 3;               // 0..7
  const int pcg = L & 7;
  const int scg = (pcg ^ srow) * 8;      // source-side swizzle

  const unsigned short* Ag = &A[(size_t)(bm + w * 32 + srow) * K + scg];
  const unsigned short* Bg = &Bt[(size_t)(bn + w * 32 + srow) * K + scg];
  unsigned short* Al = &Alds[(w * 32 + srow) * 64 + pcg * 8];
  unsigned short* Bl = &Blds[(w * 32 + srow) * 64 + pcg * 8];

  for (int k0 = 0; k0 < K; k0 += 64) {
#pragma unroll
    for (int i = 0; i < 4; i++) {
      gl2lds16(Ag + (size_t)(i * 8) * K, Al + i * 8 * 64);
      gl2lds16(Bg + (size_t)(i * 8) * K, Bl + i * 8 * 64);
    }
    Ag += 64; Bg += 64;
    __syncthreads();

#pragma unroll
    for (int kk = 0; kk < 2; kk++) {
      const int ofs = ((kk * 4 + lg) ^ (lr & 7)) * 8;
      bf16x8 af[4], bfr[4];
#pragma unroll
      for (int i = 0; i < 4; i++) {
        af[i]  = *(const bf16x8*)&Alds[(wm + i * 16 + lr) * 64 + ofs];
        bfr[i] = *(const bf16x8*)&Blds[(wn + i * 16 + lr) * 64 + ofs];
      }
#pragma unroll
      for (int mi = 0; mi < 4; mi++)
#pragma unroll
        for (int ni = 0; ni < 4; ni++)
          acc[mi][ni] = MFMA(af[mi], bfr[ni], acc[mi][ni]);
    }
    __syncthreads();
  }

#pragma unroll
  for (int mi = 0; mi < 4; mi++) {
#pragma unroll
    for (int ni = 0; ni < 4; ni++) {
#pragma unroll
      for (int r = 0; r < 4; r++) {
        size_t row = bm + wm + mi * 16 + lg * 4 + r;
        size_t col = bn + wn + ni * 16 + lr;
        float v = acc[mi][ni][r];
        if constexpr (F32OUT) ((float*)C)[row * N + col] = v;
        else ((unsigned short*)C)[row * N + col] = f2bf(v);
      }
    }
  }
}

// ---------------- RoPE in place on bf16 rows, vectorized x4 ----------------
__global__ void rope_kernel(unsigned short* __restrict__ X, const float* __restrict__ cs,
                            int H, int rowStride, int colOff, float scale) {
  int idx = blockIdx.x * 256 + threadIdx.x;
  int dg = idx & 15;            // 4-wide d group: d = dg*4..dg*4+3
  int h = (idx >> 4) % H;
  int s = idx / (16 * H);
  size_t base = (size_t)s * rowStride + colOff + (size_t)h * 128 + dg * 4;
  ushort4 xa = *(const ushort4*)&X[base];
  ushort4 xb = *(const ushort4*)&X[base + 64];
  float4 c = *(const float4*)&cs[s * 64 + dg * 4];
  float4 sn = *(const float4*)&cs[2048 * 64 + s * 64 + dg * 4];
  ushort4 oa, ob;
  {
    float x1 = bf2f(xa.x), x2 = bf2f(xb.x);
    oa.x = f2bf((x1 * c.x + x2 * sn.x) * scale);
    ob.x = f2bf((x2 * c.x - x1 * sn.x) * scale);
  }
  {
    float x1 = bf2f(xa.y), x2 = bf2f(xb.y);
    oa.y = f2bf((x1 * c.y + x2 * sn.y) * scale);
    ob.y = f2bf((x2 * c.y - x1 * sn.y) * scale);
  }
  {
    float x1 = bf2f(xa.z), x2 = bf2f(xb.z);
    oa.z = f2bf((x1 * c.z + x2 * sn.z) * scale);
    ob.z = f2bf((x2 * c.z - x1 * sn.z) * scale);
  }
  {
    float x1 = bf2f(xa.w), x2 = bf2f(xb.w);
    oa.w = f2bf((x1 * c.w + x2 * sn.w) * scale);
    ob.w = f2bf((x2 * c.w - x1 * sn.w) * scale);
  }
  *(ushort4*)&X[base] = oa;
  *(ushort4*)&X[base + 64] = ob;
}

// ---------------- V (cols 5120.. of QKV, stride 6144) -> Vt (8,128,2048) ----------------
__global__ void v_transpose(const unsigned short* __restrict__ QKV,
                            unsigned short* __restrict__ Vt) {
  __shared__ unsigned short tile[32][33];
  int h = blockIdx.z;
  int s0 = blockIdx.x * 32, d0 = blockIdx.y * 32;
  int c = threadIdx.x & 31, r0 = threadIdx.x >> 5;
#pragma unroll
  for (int i = 0; i < 32; i += 8)
    tile[r0 + i][c] = QKV[(size_t)(s0 + r0 + i) * 6144 + 5120 + h * 128 + d0 + c];
  __syncthreads();
#pragma unroll
  for (int i = 0; i < 32; i += 8)
    Vt[(size_t)(h * 128 + d0 + r0 + i) * 2048 + s0 + c] = tile[c][r0 + i];
}

// ---------------- causal flash attention (v3: pipelined K/V staging) ----------------
// R6-measured win (~-50 us vs v2 by cross-round arithmetic). K double-buffered
// (stage K[t+1] after QK^T, lands under PV); V single-buffered, staged at tile
// entry, awaited by counted WAITVM(4) after QK^T+exp.
// vmcnt ledger (per wave): entry outstanding = K[t](4) -> WAITVM(0) (issued a
// full PV earlier, cheap); mid outstanding = V[t](4)+K[t+1](4) -> WAITVM(4)
// drains V (older). t==qb: no K-stage -> WAITVM(0) at mid. Raw s_barrier only.
// Hazards: V restage at entry safe (tile t-1 PV reads drained per-wave before
// entry BARRIER); K[t+1] targets buffer last read at tile t-1 (drained before
// t-1's mid BARRIER).
__global__ __launch_bounds__(256) void flash_kernel(
    const unsigned short* __restrict__ QKV,  // (2048, 6144) roped; Q pre-scaled
    const unsigned short* __restrict__ Vt,   // (8, 128, 2048)
    unsigned short* __restrict__ O) {        // (2048, 4096)
  constexpr int PSTR = 72;
  __shared__ alignas(16) unsigned short Klds[2 * 64 * 128];   // 32 KB dbuf, swz cg16
  __shared__ alignas(16) unsigned short Vlds[128 * 64];       // 16 KB, swz cg8
  __shared__ alignas(16) unsigned short Plds[4 * 32 * PSTR];  // 18 KB wave-private
  const int tid = threadIdx.x, w = tid >> 6, L = tid & 63;
  const int lr = L & 15, lg = L >> 4;
  const int bid = blockIdx.x;
  const int hk = bid & 7;
  const int hp = (bid >> 3) & 1;
  const int qb = 31 - (bid >> 4);          // heavy blocks dispatch first
  const int hq = hk * 4 + hp * 2 + (w & 1);
  const int qr0 = qb * 64 + (w >> 1) * 32; // wave's 32 q-rows
  const unsigned short* Kg = QKV + 4096;

  // K staging: row=flat>>4, lcg=flat&15, source cg = lcg ^ (row&15)
  const int k_row = tid >> 4, k_lcg = tid & 15;
  const unsigned short* KgT = &Kg[(size_t)k_row * 6144 + hk * 128 + ((k_lcg ^ (k_row & 15)) * 8)];
  unsigned short* KlT = &Klds[k_row * 128 + k_lcg * 8];
  // V staging: row=flat>>3 (dh), lcg=flat&7, source cg = lcg ^ (row&7)
  const int v_row = tid >> 3, v_lcg = tid & 7;
  const unsigned short* VgT = &Vt[(size_t)(hk * 128 + v_row) * 2048 + ((v_lcg ^ (v_row & 7)) * 8)];
  unsigned short* VlT = &Vlds[v_row * 64 + v_lcg * 8];

  // prologue: stage K[0] into K buffer 0
#pragma unroll
  for (int i = 0; i < 4; i++)
    gl2lds16(KgT + (size_t)(i * 16) * 6144, KlT + i * 16 * 128);

  bf16x8 qf[2][4];
#pragma unroll
  for (int mi = 0; mi < 2; mi++)
#pragma unroll
    for (int c = 0; c < 4; c++)
      qf[mi][c] = *(const bf16x8*)&QKV[(size_t)(qr0 + mi * 16 + lr) * 6144 + hq * 128 + c * 32 + lg * 8];

  floatx4 oacc[2][8] = {};
  float l_lane[2][4] = {};
  unsigned short* pw = &Plds[w * 32 * PSTR];

  for (int t = 0; t <= qb; t++) {
    const int kv0 = t * 64;
    const int kb = t & 1;
    WAITVM(0);     // K[t] landed (only K[t] outstanding at entry; also drains qf at t=0)
    BARRIER();     // collective: K[t] visible; all waves' V[t-1] PV reads done
    // stage V[t] (single buffer, safe per barrier above)
#pragma unroll
    for (int i = 0; i < 4; i++)
      gl2lds16(VgT + kv0 + (size_t)(i * 32) * 2048, VlT + i * 32 * 64);

    const unsigned short* Kl = &Klds[kb * (64 * 128)];
#pragma unroll
    for (int nt = 0; nt < 4; nt++) {
      bf16x8 kf[4];
#pragma unroll
      for (int c = 0; c < 4; c++)
        kf[c] = *(const bf16x8*)&Kl[(nt * 16 + lr) * 128 + (((c * 4 + lg) ^ lr) * 8)];
      floatx4 sc[2];
#pragma unroll
      for (int mi = 0; mi < 2; mi++) {
        floatx4 a = {};
#pragma unroll
        for (int c = 0; c < 4; c++) a = MFMA(qf[mi][c], kf[c], a);
        sc[mi] = a;
      }
      if (t == qb) {  // diagonal tile: causal mask
#pragma unroll
        for (int mi = 0; mi < 2; mi++)
#pragma unroll
          for (int r = 0; r < 4; r++)
            if (kv0 + nt * 16 + lr > qr0 + mi * 16 + lg * 4 + r) sc[mi][r] = -3e38f;
      }
#pragma unroll
      for (int mi = 0; mi < 2; mi++)
#pragma unroll
        for (int r = 0; r < 4; r++) {
          float p = fast_exp2(sc[mi][r]);
          l_lane[mi][r] += p;
          pw[(mi * 16 + lg * 4 + r) * PSTR + nt * 16 + lr] = f2bf(p);
        }
    }

    // stage K[t+1] into the other K buffer (its readers drained at tile t-1)
    if (t < qb) {
      unsigned short* Kd = KlT + (kb ^ 1) * (64 * 128);
#pragma unroll
      for (int i = 0; i < 4; i++)
        gl2lds16(KgT + (size_t)(kv0 + 64 + i * 16) * 6144, Kd + i * 16 * 128);
      WAITVM(4);   // drains V[t] (older); K[t+1]'s 4 stay in flight
    } else {
      WAITVM(0);   // last tile: drain V[t]
    }
    BARRIER();     // collective: V[t] visible

    // P (wave-private, in-order DS) -> A-fragments
    bf16x8 pf[2][2];
#pragma unroll
    for (int mi = 0; mi < 2; mi++)
#pragma unroll
      for (int c = 0; c < 2; c++)
        pf[mi][c] = *(const bf16x8*)&pw[(mi * 16 + lr) * PSTR + c * 32 + lg * 8];

#pragma unroll
    for (int n = 0; n < 8; n++) {
#pragma unroll
      for (int c = 0; c < 2; c++) {
        bf16x8 vf = *(const bf16x8*)&Vlds[(n * 16 + lr) * 64 + (((c * 4 + lg) ^ (lr & 7)) * 8)];
#pragma unroll
        for (int mi = 0; mi < 2; mi++) oacc[mi][n] = MFMA(pf[mi][c], vf, oacc[mi][n]);
      }
    }
  }

  // row-sum across the 16 lr lanes (masks 1..8 stay within lr group)
  float linv[2][4];
#pragma unroll
  for (int mi = 0; mi < 2; mi++)
#pragma unroll
    for (int r = 0; r < 4; r++) {
      float l = l_lane[mi][r];
      l += __shfl_xor(l, 1);
      l += __shfl_xor(l, 2);
      l += __shfl_xor(l, 4);
      l += __shfl_xor(l, 8);
      linv[mi][r] = 1.0f / l;
    }

#pragma unroll
  for (int mi = 0; mi < 2; mi++)
#pragma unroll
    for (int n = 0; n < 8; n++)
#pragma unroll
      for (int r = 0; r < 4; r++) {
        size_t row = qr0 + mi * 16 + lg * 4 + r;
        size_t col = (size_t)hq * 128 + n * 16 + lr;
        O[row * 4096 + col] = f2bf(oacc[mi][n][r] * linv[mi][r]);
      }
}

extern "C" void kernel_launch(void* const* d_in, const int* in_sizes, int n_in,
                              void* d_out, int out_size, void* d_ws, size_t ws_size,
                              hipStream_t stream) {
  const float* x  = (const float*)d_in[0];
  const float* cs = (const float*)d_in[1];
  const float* wq = (const float*)d_in[2];
  const float* wk = (const float*)d_in[3];
  const float* wv = (const float*)d_in[4];
  const float* wo = (const float*)d_in[5];
  float* out = (float*)d_out;

  char* ws = (char*)d_ws;
  unsigned short* xb   = (unsigned short*)(ws);               // 16 MB  x bf16
  unsigned short* wqt  = (unsigned short*)(ws + 16777216);    // 32 MB  wq^T } contiguous
  unsigned short* wkt  = (unsigned short*)(ws + 50331648);    // 8 MB   wk^T } B for fused
  unsigned short* wvt  = (unsigned short*)(ws + 58720256);    // 8 MB   wv^T } QKV gemm
  unsigned short* wot  = (unsigned short*)(ws + 67108864);    // 32 MB  wo^T
  unsigned short* QKVb = (unsigned short*)(ws + 100663296);   // 24 MB  [Q|K|V]
  unsigned short* Vtb  = (unsigned short*)(ws + 125829120);   // 4 MB   V^T
  unsigned short* Ob   = xb;  // alias: xb dead after QKV gemm

  convert_f32_bf16<<<8192, 256, 0, stream>>>(x, xb, 2097152);
  transpose_f32_bf16<<<dim3(64, 64), 256, 0, stream>>>(wq, wqt, 4096, 4096);
  transpose_f32_bf16<<<dim3(16, 64), 256, 0, stream>>>(wk, wkt, 4096, 1024);
  transpose_f32_bf16<<<dim3(16, 64), 256, 0, stream>>>(wv, wvt, 4096, 1024);
  transpose_f32_bf16<<<dim3(64, 64), 256, 0, stream>>>(wo, wot, 4096, 4096);

  // QKV: gemm_bt (R0-measured 118 us), grid (48,16)
  gemm_bt<false><<<dim3(48, 16), 256, 0, stream>>>(xb, wqt, QKVb, 2048, 6144, 4096);

  // Q scale folds softmax 1/sqrt(128) AND log2(e) for exp2-based softmax
  rope_kernel<<<4096, 256, 0, stream>>>(QKVb, cs, 32, 6144, 0, 0.12751743f);
  rope_kernel<<<1024, 256, 0, stream>>>(QKVb, cs, 8, 6144, 4096, 1.0f);

  v_transpose<<<dim3(64, 4, 8), 256, 0, stream>>>(QKVb, Vtb);

  flash_kernel<<<512, 256, 0, stream>>>(QKVb, Vtb, Ob);

  // O-proj: gemm_bt, grid (32,16)
  gemm_bt<true><<<dim3(32, 16), 256, 0, stream>>>(Ob, wot, out, 2048, 4096, 4096);
}